// Round 1
// baseline (1567.188 us; speedup 1.0000x reference)
//
#include <hip/hip_runtime.h>
#include <hip/hip_bf16.h>
#include <math.h>

#define NN 50000
#define NE 800000
#define NGRAPH 128
#define HEADS 8
#define CH 32
#define HID 256
#define NEG_SLOPE 0.2f

// ---------------- CSR build ----------------

__global__ void init_counts_kernel(int* counts, int n) {
    int i = blockIdx.x * blockDim.x + threadIdx.x;
    if (i < n) counts[i] = 1;  // self-loop
}

__global__ void count_edges_kernel(const int* __restrict__ dst, int* counts, int e) {
    int i = blockIdx.x * blockDim.x + threadIdx.x;
    if (i < e) atomicAdd(&counts[dst[i]], 1);
}

// single-block exclusive scan over counts -> row_ptr (n+1), also fill cursor
__global__ __launch_bounds__(1024) void scan_kernel(const int* __restrict__ counts,
                                                    int* row_ptr, int* cursor, int n) {
    __shared__ int tile[1024];
    __shared__ int carry_s;
    int tid = threadIdx.x;
    if (tid == 0) carry_s = 0;
    __syncthreads();
    for (int base = 0; base < n; base += 1024) {
        int i = base + tid;
        int v = (i < n) ? counts[i] : 0;
        tile[tid] = v;
        __syncthreads();
        for (int off = 1; off < 1024; off <<= 1) {
            int t = (tid >= off) ? tile[tid - off] : 0;
            __syncthreads();
            tile[tid] += t;
            __syncthreads();
        }
        int incl = tile[tid];
        int c = carry_s;
        if (i < n) { row_ptr[i] = c + incl - v; cursor[i] = c + incl - v; }
        __syncthreads();
        if (tid == 1023) carry_s = c + incl;
        __syncthreads();
    }
    if (tid == 0) row_ptr[n] = carry_s;
}

__global__ void scatter_kernel(const int* __restrict__ ei, int* cursor, int* srcs, int ne, int nn) {
    int i = blockIdx.x * blockDim.x + threadIdx.x;
    if (i < ne) {
        int s = ei[i];
        int d = ei[ne + i];
        int pos = atomicAdd(&cursor[d], 1);
        srcs[pos] = s;
    } else if (i < ne + nn) {
        int v = i - ne;
        int pos = atomicAdd(&cursor[v], 1);
        srcs[pos] = v;
    }
}

// ---------------- GEMM: C[M,256] = A[M,K] @ W[K,256] (no bias) ----------------

#define TM 64
#define TN 64
#define TK 16

__global__ __launch_bounds__(256) void gemm_kernel(const float* __restrict__ A,
                                                   const float* __restrict__ W,
                                                   float* __restrict__ C,
                                                   int M, int K) {
    __shared__ float As[TK][TM];
    __shared__ float Bs[TK][TN];
    int m0 = blockIdx.x * TM;
    int n0 = blockIdx.y * TN;
    int t = threadIdx.x;
    int tx = t & 15, ty = t >> 4;

    float acc[4][4] = {};

    int arow = t >> 2, akg = t & 3;      // A-tile load: 64 rows x (4 groups of 4 k)
    for (int kt = 0; kt < K; kt += TK) {
        int gr = m0 + arow; if (gr >= M) gr = M - 1;
        float4 a4 = *(const float4*)&A[(size_t)gr * K + kt + akg * 4];
        As[akg * 4 + 0][arow] = a4.x;
        As[akg * 4 + 1][arow] = a4.y;
        As[akg * 4 + 2][arow] = a4.z;
        As[akg * 4 + 3][arow] = a4.w;
        // B-tile: 16 k-rows x 64 cols
        float4 b4 = *(const float4*)&W[(size_t)(kt + ty) * 256 + n0 + tx * 4];
        *(float4*)&Bs[ty][tx * 4] = b4;
        __syncthreads();
#pragma unroll
        for (int k = 0; k < TK; k++) {
            float4 av = *(const float4*)&As[k][ty * 4];
            float4 bv = *(const float4*)&Bs[k][tx * 4];
            float a[4] = {av.x, av.y, av.z, av.w};
            float b[4] = {bv.x, bv.y, bv.z, bv.w};
#pragma unroll
            for (int i = 0; i < 4; i++)
#pragma unroll
                for (int j = 0; j < 4; j++) acc[i][j] += a[i] * b[j];
        }
        __syncthreads();
    }
#pragma unroll
    for (int i = 0; i < 4; i++) {
        int r = m0 + ty * 4 + i;
        if (r < M) {
            float4 o = make_float4(acc[i][0], acc[i][1], acc[i][2], acc[i][3]);
            *(float4*)&C[(size_t)r * 256 + n0 + tx * 4] = o;
        }
    }
}

// ---------------- attention logits per node/head ----------------

__global__ void alpha_kernel(const float* __restrict__ h, const float* __restrict__ a_src,
                             const float* __restrict__ a_dst, float* __restrict__ alS,
                             float* __restrict__ alD, int n) {
    int idx = blockIdx.x * blockDim.x + threadIdx.x;  // node*8 + head
    if (idx >= n * HEADS) return;
    int head = idx & 7;
    int node = idx >> 3;
    const float* hp = h + (size_t)node * HID + head * CH;
    const float* as = a_src + head * CH;
    const float* ad = a_dst + head * CH;
    float s1 = 0.f, s2 = 0.f;
#pragma unroll
    for (int c = 0; c < CH; c++) {
        float v = hp[c];
        s1 += v * as[c];
        s2 += v * ad[c];
    }
    alS[idx] = s1;
    alD[idx] = s2;
}

// ---------------- per-dst softmax attention aggregation ----------------

__global__ __launch_bounds__(256) void aggregate_kernel(const float* __restrict__ hpre,
                                                        const float* __restrict__ alS,
                                                        const float* __restrict__ alD,
                                                        const int* __restrict__ row_ptr,
                                                        const int* __restrict__ srcs,
                                                        const float* __restrict__ bias,
                                                        float* __restrict__ out) {
    int n = blockIdx.x;
    int t = threadIdx.x;          // = head*32 + c
    int head = t >> 5;
    int lo = row_ptr[n], hi = row_ptr[n + 1];
    float ald = alD[n * HEADS + head];

    float m = -1e30f;
    for (int i = lo; i < hi; i++) {
        int s = srcs[i];
        float e = alS[s * HEADS + head] + ald;
        e = e > 0.f ? e : NEG_SLOPE * e;
        m = fmaxf(m, e);
    }
    float denom = 0.f, acc = 0.f;
    for (int i = lo; i < hi; i++) {
        int s = srcs[i];
        float e = alS[s * HEADS + head] + ald;
        e = e > 0.f ? e : NEG_SLOPE * e;
        float w = __expf(e - m);
        denom += w;
        acc += w * hpre[(size_t)s * HID + t];
    }
    out[(size_t)n * HID + t] = acc / (denom + 1e-16f) + bias[t];
}

// ---------------- mean pool per graph ----------------

__global__ __launch_bounds__(256) void pool_kernel(const float* __restrict__ h,
                                                   const int* __restrict__ batch,
                                                   float* __restrict__ pooled, int n) {
    int g = blockIdx.x;
    int t = threadIdx.x;
    int lo = 0, hi = n;
    while (lo < hi) { int mid = (lo + hi) >> 1; if (batch[mid] < g) lo = mid + 1; else hi = mid; }
    int start = lo;
    lo = 0; hi = n;
    while (lo < hi) { int mid = (lo + hi) >> 1; if (batch[mid] < g + 1) lo = mid + 1; else hi = mid; }
    int end = lo;
    float acc = 0.f;
    for (int i = start; i < end; i++) acc += h[(size_t)i * HID + t];
    int cnt = end - start;
    pooled[g * HID + t] = acc / (float)(cnt > 0 ? cnt : 1);
}

// ---------------- final linear 128x256 @ 256x10 ----------------

__global__ void final_kernel(const float* __restrict__ pooled, const float* __restrict__ W,
                             const float* __restrict__ b, float* __restrict__ out) {
    int idx = blockIdx.x * blockDim.x + threadIdx.x;
    if (idx >= NGRAPH * 10) return;
    int g = idx / 10, o = idx % 10;
    float acc = b[o];
    for (int k = 0; k < HID; k++) acc += pooled[g * HID + k] * W[k * 10 + o];
    out[idx] = acc;
}

extern "C" void kernel_launch(void* const* d_in, const int* in_sizes, int n_in,
                              void* d_out, int out_size, void* d_ws, size_t ws_size,
                              hipStream_t stream) {
    const float* x      = (const float*)d_in[0];
    const int*   ei     = (const int*)d_in[1];
    const int*   batch  = (const int*)d_in[2];
    const float* W0     = (const float*)d_in[3];
    const float* a_src0 = (const float*)d_in[4];
    const float* a_dst0 = (const float*)d_in[5];
    const float* b0     = (const float*)d_in[6];
    const float* Wh     = (const float*)d_in[7];   // [2,256,256]
    const float* a_srch = (const float*)d_in[8];   // [2,8,32]
    const float* a_dsth = (const float*)d_in[9];
    const float* bh     = (const float*)d_in[10];  // [2,256]
    const float* W_lin  = (const float*)d_in[11];
    const float* b_lin  = (const float*)d_in[12];
    float* out = (float*)d_out;

    // workspace carve-up
    float* bufA   = (float*)d_ws;                  // 50000*256
    float* bufB   = bufA + (size_t)NN * HID;       // 50000*256
    float* alS    = bufB + (size_t)NN * HID;       // 50000*8
    float* alD    = alS + (size_t)NN * HEADS;
    float* pooled = alD + (size_t)NN * HEADS;      // 128*256
    int* counts   = (int*)(pooled + NGRAPH * HID); // 50000
    int* row_ptr  = counts + NN;                   // 50001
    int* cursor   = row_ptr + NN + 1;              // 50000
    int* srcs     = cursor + NN;                   // 850000

    const int NEP = NE + NN;  // edges incl self-loops

    // CSR build
    init_counts_kernel<<<(NN + 255) / 256, 256, 0, stream>>>(counts, NN);
    count_edges_kernel<<<(NE + 255) / 256, 256, 0, stream>>>(ei + NE, counts, NE);
    scan_kernel<<<1, 1024, 0, stream>>>(counts, row_ptr, cursor, NN);
    scatter_kernel<<<(NEP + 255) / 256, 256, 0, stream>>>(ei, cursor, srcs, NE, NN);

    dim3 gemm_grid((NN + TM - 1) / TM, HID / TN);

    // layer 0: x[.,128] @ W0 -> bufA ; aggregate -> bufB
    gemm_kernel<<<gemm_grid, 256, 0, stream>>>(x, W0, bufA, NN, 128);
    alpha_kernel<<<(NN * HEADS + 255) / 256, 256, 0, stream>>>(bufA, a_src0, a_dst0, alS, alD, NN);
    aggregate_kernel<<<NN, 256, 0, stream>>>(bufA, alS, alD, row_ptr, srcs, b0, bufB);

    // hidden layers
    for (int l = 0; l < 2; l++) {
        const float* W = Wh + (size_t)l * HID * HID;
        const float* as = a_srch + (size_t)l * HEADS * CH;
        const float* ad = a_dsth + (size_t)l * HEADS * CH;
        const float* bb = bh + (size_t)l * HID;
        gemm_kernel<<<gemm_grid, 256, 0, stream>>>(bufB, W, bufA, NN, HID);
        alpha_kernel<<<(NN * HEADS + 255) / 256, 256, 0, stream>>>(bufA, as, ad, alS, alD, NN);
        aggregate_kernel<<<NN, 256, 0, stream>>>(bufA, alS, alD, row_ptr, srcs, bb, bufB);
    }

    // pool + final linear
    pool_kernel<<<NGRAPH, 256, 0, stream>>>(bufB, batch, pooled, NN);
    final_kernel<<<(NGRAPH * 10 + 255) / 256, 256, 0, stream>>>(pooled, W_lin, b_lin, out);
}

// Round 2
// 1068.370 us; speedup vs baseline: 1.4669x; 1.4669x over previous
//
#include <hip/hip_runtime.h>
#include <hip/hip_bf16.h>
#include <math.h>

#define NN 50000
#define NE 800000
#define NGRAPH 128
#define HEADS 8
#define CH 32
#define HID 256
#define NEG_SLOPE 0.2f

// ---------------- CSR build ----------------

__global__ void init_counts_kernel(int* counts, int n) {
    int i = blockIdx.x * blockDim.x + threadIdx.x;
    if (i < n) counts[i] = 1;  // self-loop
}

__global__ void count_edges_kernel(const int* __restrict__ dst, int* counts, int e) {
    int i = blockIdx.x * blockDim.x + threadIdx.x;
    if (i < e) atomicAdd(&counts[dst[i]], 1);
}

__device__ inline int wave_incl_scan(int v, int lane) {
#pragma unroll
    for (int off = 1; off < 64; off <<= 1) {
        int u = __shfl_up(v, off);
        if (lane >= off) v += u;
    }
    return v;
}

// per-1024-chunk totals
__global__ __launch_bounds__(1024) void scan_part_kernel(const int* __restrict__ counts,
                                                         int* partial, int n) {
    int i = blockIdx.x * 1024 + threadIdx.x;
    int v = (i < n) ? counts[i] : 0;
    int lane = threadIdx.x & 63, w = threadIdx.x >> 6;
    __shared__ int ws[16];
    int sv = wave_incl_scan(v, lane);
    if (lane == 63) ws[w] = sv;
    __syncthreads();
    if (threadIdx.x == 0) {
        int tot = 0;
#pragma unroll
        for (int j = 0; j < 16; j++) tot += ws[j];
        partial[blockIdx.x] = tot;
    }
}

// exclusive scan of partials (nb <= 64), single wave
__global__ void scan_offsets_kernel(const int* __restrict__ partial, int* blockOff, int nb) {
    int lane = threadIdx.x;
    int v = (lane < nb) ? partial[lane] : 0;
    int incl = wave_incl_scan(v, lane);
    if (lane < nb) blockOff[lane] = incl - v;
}

// final: local scan + offset -> row_ptr (exclusive) + cursor
__global__ __launch_bounds__(1024) void scan_final_kernel(const int* __restrict__ counts,
                                                          const int* __restrict__ blockOff,
                                                          int* row_ptr, int* cursor, int n) {
    int i = blockIdx.x * 1024 + threadIdx.x;
    int v = (i < n) ? counts[i] : 0;
    int lane = threadIdx.x & 63, w = threadIdx.x >> 6;
    __shared__ int ws[17];
    int sv = wave_incl_scan(v, lane);
    if (lane == 63) ws[w] = sv;
    __syncthreads();
    if (w == 0) {
        int t = (lane < 16) ? ws[lane] : 0;
        int ts = wave_incl_scan(t, lane);
        if (lane < 16) ws[lane] = ts;
    }
    __syncthreads();
    int waveBase = (w > 0) ? ws[w - 1] : 0;
    int off = blockOff[blockIdx.x];
    int incl = waveBase + sv;
    if (i < n) {
        int ex = off + incl - v;
        row_ptr[i] = ex;
        cursor[i] = ex;
        if (i == n - 1) row_ptr[n] = off + incl;
    }
}

__global__ void scatter_kernel(const int* __restrict__ ei, int* cursor, int* srcs, int ne, int nn) {
    int i = blockIdx.x * blockDim.x + threadIdx.x;
    if (i < ne) {
        int s = ei[i];
        int d = ei[ne + i];
        int pos = atomicAdd(&cursor[d], 1);
        srcs[pos] = s;
    } else if (i < ne + nn) {
        int v = i - ne;
        int pos = atomicAdd(&cursor[v], 1);
        srcs[pos] = v;
    }
}

// ---------------- GEMM: C[M,256] = A[M,K] @ W[K,256], 128x128 tile, 8x8 micro ----------------

#define GTM 128
#define GTN 128
#define GTK 16

__global__ __launch_bounds__(256) void gemm_kernel(const float* __restrict__ A,
                                                   const float* __restrict__ W,
                                                   float* __restrict__ C,
                                                   int M, int K) {
    __shared__ float As[GTK][GTM];
    __shared__ float Bs[GTK][GTN];
    int m0 = blockIdx.x * GTM;
    int n0 = blockIdx.y * GTN;
    int t = threadIdx.x;
    int tx = t & 15, ty = t >> 4;

    float acc[8][8] = {};

    // A load mapping: row = t & 127, khalf = t >> 7 (8 consecutive k)
    int arow = t & 127, akh = (t >> 7) * 8;
    // B load mapping: col4 = (t & 31)*4, krow = t >> 5 (0..7), plus krow+8
    int bcol = (t & 31) * 4, bk = t >> 5;

    for (int kt = 0; kt < K; kt += GTK) {
        int gr = m0 + arow;
        if (gr >= M) gr = M - 1;
        float4 a0 = *(const float4*)&A[(size_t)gr * K + kt + akh];
        float4 a1 = *(const float4*)&A[(size_t)gr * K + kt + akh + 4];
        As[akh + 0][arow] = a0.x; As[akh + 1][arow] = a0.y;
        As[akh + 2][arow] = a0.z; As[akh + 3][arow] = a0.w;
        As[akh + 4][arow] = a1.x; As[akh + 5][arow] = a1.y;
        As[akh + 6][arow] = a1.z; As[akh + 7][arow] = a1.w;
        float4 b0 = *(const float4*)&W[(size_t)(kt + bk) * 256 + n0 + bcol];
        float4 b1 = *(const float4*)&W[(size_t)(kt + bk + 8) * 256 + n0 + bcol];
        *(float4*)&Bs[bk][bcol] = b0;
        *(float4*)&Bs[bk + 8][bcol] = b1;
        __syncthreads();
#pragma unroll
        for (int k = 0; k < GTK; k++) {
            float4 a0v = *(const float4*)&As[k][ty * 4];
            float4 a1v = *(const float4*)&As[k][ty * 4 + 64];
            float4 b0v = *(const float4*)&Bs[k][tx * 4];
            float4 b1v = *(const float4*)&Bs[k][tx * 4 + 64];
            float av[8] = {a0v.x, a0v.y, a0v.z, a0v.w, a1v.x, a1v.y, a1v.z, a1v.w};
            float bv[8] = {b0v.x, b0v.y, b0v.z, b0v.w, b1v.x, b1v.y, b1v.z, b1v.w};
#pragma unroll
            for (int i = 0; i < 8; i++)
#pragma unroll
                for (int j = 0; j < 8; j++) acc[i][j] += av[i] * bv[j];
        }
        __syncthreads();
    }
#pragma unroll
    for (int i = 0; i < 8; i++) {
        int r = m0 + (i < 4 ? ty * 4 + i : 64 + ty * 4 + (i - 4));
        if (r < M) {
            float4 o0 = make_float4(acc[i][0], acc[i][1], acc[i][2], acc[i][3]);
            float4 o1 = make_float4(acc[i][4], acc[i][5], acc[i][6], acc[i][7]);
            *(float4*)&C[(size_t)r * 256 + n0 + tx * 4] = o0;
            *(float4*)&C[(size_t)r * 256 + n0 + tx * 4 + 64] = o1;
        }
    }
}

// ---------------- attention logits per node/head ----------------

__global__ void alpha_kernel(const float* __restrict__ h, const float* __restrict__ a_src,
                             const float* __restrict__ a_dst, float* __restrict__ alS,
                             float* __restrict__ alD, int n) {
    int idx = blockIdx.x * blockDim.x + threadIdx.x;  // node*8 + head
    if (idx >= n * HEADS) return;
    int head = idx & 7;
    int node = idx >> 3;
    const float* hp = h + (size_t)node * HID + head * CH;
    const float* as = a_src + head * CH;
    const float* ad = a_dst + head * CH;
    float s1 = 0.f, s2 = 0.f;
#pragma unroll
    for (int c = 0; c < CH; c++) {
        float v = hp[c];
        s1 += v * as[c];
        s2 += v * ad[c];
    }
    alS[idx] = s1;
    alD[idx] = s2;
}

// ---------------- attention stats: per (node,head) max + denom ----------------
// one wave per node; lane = edge_sub*8 + head

__global__ __launch_bounds__(256) void att_stats_kernel(const float* __restrict__ alS,
                                                        const float* __restrict__ alD,
                                                        const int* __restrict__ row_ptr,
                                                        const int* __restrict__ srcs,
                                                        float* __restrict__ mArr,
                                                        float* __restrict__ dArr, int n) {
    int node = blockIdx.x * 4 + (threadIdx.x >> 6);
    if (node >= n) return;
    int lane = threadIdx.x & 63;
    int eh = lane >> 3, head = lane & 7;
    int lo = row_ptr[node], hi = row_ptr[node + 1];
    float ald = alD[node * HEADS + head];

    float m = -1e30f;
    for (int base = lo; base < hi; base += 8) {
        int i = base + eh;
        float e = -1e30f;
        if (i < hi) {
            int s = srcs[i];
            e = alS[s * HEADS + head] + ald;
            e = e > 0.f ? e : NEG_SLOPE * e;
        }
        m = fmaxf(m, e);
    }
    m = fmaxf(m, __shfl_xor(m, 8));
    m = fmaxf(m, __shfl_xor(m, 16));
    m = fmaxf(m, __shfl_xor(m, 32));

    float denom = 0.f;
    for (int base = lo; base < hi; base += 8) {
        int i = base + eh;
        if (i < hi) {
            int s = srcs[i];
            float e = alS[s * HEADS + head] + ald;
            e = e > 0.f ? e : NEG_SLOPE * e;
            denom += __expf(e - m);
        }
    }
    denom += __shfl_xor(denom, 8);
    denom += __shfl_xor(denom, 16);
    denom += __shfl_xor(denom, 32);

    if (eh == 0) {
        mArr[node * HEADS + head] = m;
        dArr[node * HEADS + head] = denom;
    }
}

// ---------------- attention apply: weighted gather, one wave per node ----------------
// lane owns channels [lane*4, lane*4+4); head = lane>>3

__global__ __launch_bounds__(256) void att_apply_kernel(const float* __restrict__ h,
                                                        const float* __restrict__ alS,
                                                        const float* __restrict__ alD,
                                                        const float* __restrict__ mArr,
                                                        const float* __restrict__ dArr,
                                                        const int* __restrict__ row_ptr,
                                                        const int* __restrict__ srcs,
                                                        const float* __restrict__ bias,
                                                        float* __restrict__ out, int n) {
    int node = blockIdx.x * 4 + (threadIdx.x >> 6);
    if (node >= n) return;
    int lane = threadIdx.x & 63;
    int head = lane >> 3;
    int lo = row_ptr[node], hi = row_ptr[node + 1];
    float ald = alD[node * HEADS + head];
    float m = mArr[node * HEADS + head];
    float inv = 1.0f / (dArr[node * HEADS + head] + 1e-16f);

    float4 acc = make_float4(0.f, 0.f, 0.f, 0.f);
    int i = lo;
    for (; i + 2 <= hi; i += 2) {
        int s0 = srcs[i], s1 = srcs[i + 1];
        float e0 = alS[s0 * HEADS + head] + ald;
        float e1 = alS[s1 * HEADS + head] + ald;
        e0 = e0 > 0.f ? e0 : NEG_SLOPE * e0;
        e1 = e1 > 0.f ? e1 : NEG_SLOPE * e1;
        float w0 = __expf(e0 - m);
        float w1 = __expf(e1 - m);
        float4 h0 = *(const float4*)&h[(size_t)s0 * HID + lane * 4];
        float4 h1 = *(const float4*)&h[(size_t)s1 * HID + lane * 4];
        acc.x += w0 * h0.x + w1 * h1.x;
        acc.y += w0 * h0.y + w1 * h1.y;
        acc.z += w0 * h0.z + w1 * h1.z;
        acc.w += w0 * h0.w + w1 * h1.w;
    }
    if (i < hi) {
        int s0 = srcs[i];
        float e0 = alS[s0 * HEADS + head] + ald;
        e0 = e0 > 0.f ? e0 : NEG_SLOPE * e0;
        float w0 = __expf(e0 - m);
        float4 h0 = *(const float4*)&h[(size_t)s0 * HID + lane * 4];
        acc.x += w0 * h0.x;
        acc.y += w0 * h0.y;
        acc.z += w0 * h0.z;
        acc.w += w0 * h0.w;
    }
    float4 b4 = *(const float4*)&bias[lane * 4];
    float4 o;
    o.x = acc.x * inv + b4.x;
    o.y = acc.y * inv + b4.y;
    o.z = acc.z * inv + b4.z;
    o.w = acc.w * inv + b4.w;
    *(float4*)&out[(size_t)node * HID + lane * 4] = o;
}

// ---------------- mean pool per graph ----------------

__global__ __launch_bounds__(256) void pool_kernel(const float* __restrict__ h,
                                                   const int* __restrict__ batch,
                                                   float* __restrict__ pooled, int n) {
    int g = blockIdx.x;
    int t = threadIdx.x;
    int lo = 0, hi = n;
    while (lo < hi) { int mid = (lo + hi) >> 1; if (batch[mid] < g) lo = mid + 1; else hi = mid; }
    int start = lo;
    lo = 0; hi = n;
    while (lo < hi) { int mid = (lo + hi) >> 1; if (batch[mid] < g + 1) lo = mid + 1; else hi = mid; }
    int end = lo;
    float acc = 0.f;
    for (int i = start; i < end; i++) acc += h[(size_t)i * HID + t];
    int cnt = end - start;
    pooled[g * HID + t] = acc / (float)(cnt > 0 ? cnt : 1);
}

// ---------------- final linear 128x256 @ 256x10 ----------------

__global__ void final_kernel(const float* __restrict__ pooled, const float* __restrict__ W,
                             const float* __restrict__ b, float* __restrict__ out) {
    int idx = blockIdx.x * blockDim.x + threadIdx.x;
    if (idx >= NGRAPH * 10) return;
    int g = idx / 10, o = idx % 10;
    float acc = b[o];
    for (int k = 0; k < HID; k++) acc += pooled[g * HID + k] * W[k * 10 + o];
    out[idx] = acc;
}

extern "C" void kernel_launch(void* const* d_in, const int* in_sizes, int n_in,
                              void* d_out, int out_size, void* d_ws, size_t ws_size,
                              hipStream_t stream) {
    const float* x      = (const float*)d_in[0];
    const int*   ei     = (const int*)d_in[1];
    const int*   batch  = (const int*)d_in[2];
    const float* W0     = (const float*)d_in[3];
    const float* a_src0 = (const float*)d_in[4];
    const float* a_dst0 = (const float*)d_in[5];
    const float* b0     = (const float*)d_in[6];
    const float* Wh     = (const float*)d_in[7];   // [2,256,256]
    const float* a_srch = (const float*)d_in[8];   // [2,8,32]
    const float* a_dsth = (const float*)d_in[9];
    const float* bh     = (const float*)d_in[10];  // [2,256]
    const float* W_lin  = (const float*)d_in[11];
    const float* b_lin  = (const float*)d_in[12];
    float* out = (float*)d_out;

    // workspace carve-up
    float* bufA   = (float*)d_ws;                  // 50000*256
    float* bufB   = bufA + (size_t)NN * HID;       // 50000*256
    float* alS    = bufB + (size_t)NN * HID;       // 50000*8
    float* alD    = alS + (size_t)NN * HEADS;
    float* mArr   = alD + (size_t)NN * HEADS;      // 50000*8
    float* dArr   = mArr + (size_t)NN * HEADS;     // 50000*8
    float* pooled = dArr + (size_t)NN * HEADS;     // 128*256
    int* counts   = (int*)(pooled + NGRAPH * HID); // 50000
    int* row_ptr  = counts + NN;                   // 50001
    int* cursor   = row_ptr + NN + 1;              // 50000
    int* srcs     = cursor + NN;                   // 850000
    int* partial  = srcs + (NE + NN);              // 64
    int* blockOff = partial + 64;                  // 64

    const int NEP = NE + NN;  // edges incl self-loops
    const int NB_SCAN = (NN + 1023) / 1024;        // 49

    // CSR build
    init_counts_kernel<<<(NN + 255) / 256, 256, 0, stream>>>(counts, NN);
    count_edges_kernel<<<(NE + 255) / 256, 256, 0, stream>>>(ei + NE, counts, NE);
    scan_part_kernel<<<NB_SCAN, 1024, 0, stream>>>(counts, partial, NN);
    scan_offsets_kernel<<<1, 64, 0, stream>>>(partial, blockOff, NB_SCAN);
    scan_final_kernel<<<NB_SCAN, 1024, 0, stream>>>(counts, blockOff, row_ptr, cursor, NN);
    scatter_kernel<<<(NEP + 255) / 256, 256, 0, stream>>>(ei, cursor, srcs, NE, NN);

    dim3 gemm_grid((NN + GTM - 1) / GTM, HID / GTN);
    const int agg_grid = (NN + 3) / 4;

    // layer 0
    gemm_kernel<<<gemm_grid, 256, 0, stream>>>(x, W0, bufA, NN, 128);
    alpha_kernel<<<(NN * HEADS + 255) / 256, 256, 0, stream>>>(bufA, a_src0, a_dst0, alS, alD, NN);
    att_stats_kernel<<<agg_grid, 256, 0, stream>>>(alS, alD, row_ptr, srcs, mArr, dArr, NN);
    att_apply_kernel<<<agg_grid, 256, 0, stream>>>(bufA, alS, alD, mArr, dArr, row_ptr, srcs, b0, bufB, NN);

    // hidden layers
    for (int l = 0; l < 2; l++) {
        const float* W = Wh + (size_t)l * HID * HID;
        const float* as = a_srch + (size_t)l * HEADS * CH;
        const float* ad = a_dsth + (size_t)l * HEADS * CH;
        const float* bb = bh + (size_t)l * HID;
        gemm_kernel<<<gemm_grid, 256, 0, stream>>>(bufB, W, bufA, NN, HID);
        alpha_kernel<<<(NN * HEADS + 255) / 256, 256, 0, stream>>>(bufA, as, ad, alS, alD, NN);
        att_stats_kernel<<<agg_grid, 256, 0, stream>>>(alS, alD, row_ptr, srcs, mArr, dArr, NN);
        att_apply_kernel<<<agg_grid, 256, 0, stream>>>(bufA, alS, alD, mArr, dArr, row_ptr, srcs, bb, bufB, NN);
    }

    // pool + final linear
    pool_kernel<<<NGRAPH, 256, 0, stream>>>(bufB, batch, pooled, NN);
    final_kernel<<<(NGRAPH * 10 + 255) / 256, 256, 0, stream>>>(pooled, W_lin, b_lin, out);
}

// Round 3
// 782.707 us; speedup vs baseline: 2.0023x; 1.3650x over previous
//
#include <hip/hip_runtime.h>
#include <hip/hip_bf16.h>
#include <math.h>

#define NN 50000
#define NE 800000
#define NGRAPH 128
#define HEADS 8
#define CH 32
#define HID 256
#define NEG_SLOPE 0.2f

typedef __attribute__((ext_vector_type(8))) short short8;
typedef __attribute__((ext_vector_type(4))) float v4f;

__device__ inline float bflo(unsigned u) { return __builtin_bit_cast(float, u << 16); }
__device__ inline float bfhi(unsigned u) { return __builtin_bit_cast(float, u & 0xFFFF0000u); }
__device__ inline short f2bf(float f) {
    __hip_bfloat16 b = __float2bfloat16(f);
    return __builtin_bit_cast(short, b);
}
__device__ inline short8 cvt_frag(float4 a0, float4 a1) {
    union { short8 s; __hip_bfloat162 b[4]; } u;
    u.b[0] = __float22bfloat162_rn(make_float2(a0.x, a0.y));
    u.b[1] = __float22bfloat162_rn(make_float2(a0.z, a0.w));
    u.b[2] = __float22bfloat162_rn(make_float2(a1.x, a1.y));
    u.b[3] = __float22bfloat162_rn(make_float2(a1.z, a1.w));
    return u.s;
}

// ---------------- CSR build ----------------

__global__ void init_counts_kernel(int* counts, int n) {
    int i = blockIdx.x * blockDim.x + threadIdx.x;
    if (i < n) counts[i] = 1;  // self-loop
}

__global__ void count_edges_kernel(const int* __restrict__ dst, int* counts, int e) {
    int i = blockIdx.x * blockDim.x + threadIdx.x;
    if (i < e) atomicAdd(&counts[dst[i]], 1);
}

__device__ inline int wave_incl_scan(int v, int lane) {
#pragma unroll
    for (int off = 1; off < 64; off <<= 1) {
        int u = __shfl_up(v, off);
        if (lane >= off) v += u;
    }
    return v;
}

__global__ __launch_bounds__(1024) void scan_part_kernel(const int* __restrict__ counts,
                                                         int* partial, int n) {
    int i = blockIdx.x * 1024 + threadIdx.x;
    int v = (i < n) ? counts[i] : 0;
    int lane = threadIdx.x & 63, w = threadIdx.x >> 6;
    __shared__ int ws[16];
    int sv = wave_incl_scan(v, lane);
    if (lane == 63) ws[w] = sv;
    __syncthreads();
    if (threadIdx.x == 0) {
        int tot = 0;
#pragma unroll
        for (int j = 0; j < 16; j++) tot += ws[j];
        partial[blockIdx.x] = tot;
    }
}

__global__ void scan_offsets_kernel(const int* __restrict__ partial, int* blockOff, int nb) {
    int lane = threadIdx.x;
    int v = (lane < nb) ? partial[lane] : 0;
    int incl = wave_incl_scan(v, lane);
    if (lane < nb) blockOff[lane] = incl - v;
}

__global__ __launch_bounds__(1024) void scan_final_kernel(const int* __restrict__ counts,
                                                          const int* __restrict__ blockOff,
                                                          int* row_ptr, int* cursor, int n) {
    int i = blockIdx.x * 1024 + threadIdx.x;
    int v = (i < n) ? counts[i] : 0;
    int lane = threadIdx.x & 63, w = threadIdx.x >> 6;
    __shared__ int ws[17];
    int sv = wave_incl_scan(v, lane);
    if (lane == 63) ws[w] = sv;
    __syncthreads();
    if (w == 0) {
        int t = (lane < 16) ? ws[lane] : 0;
        int ts = wave_incl_scan(t, lane);
        if (lane < 16) ws[lane] = ts;
    }
    __syncthreads();
    int waveBase = (w > 0) ? ws[w - 1] : 0;
    int off = blockOff[blockIdx.x];
    int incl = waveBase + sv;
    if (i < n) {
        int ex = off + incl - v;
        row_ptr[i] = ex;
        cursor[i] = ex;
        if (i == n - 1) row_ptr[n] = off + incl;
    }
}

__global__ void scatter_kernel(const int* __restrict__ ei, int* cursor, int* srcs, int ne, int nn) {
    int i = blockIdx.x * blockDim.x + threadIdx.x;
    if (i < ne) {
        int s = ei[i];
        int d = ei[ne + i];
        int pos = atomicAdd(&cursor[d], 1);
        srcs[pos] = s;
    } else if (i < ne + nn) {
        int v = i - ne;
        int pos = atomicAdd(&cursor[v], 1);
        srcs[pos] = v;
    }
}

// ---------------- W convert+transpose: W[K,256] f32 -> Wt[256,K] bf16 ----------------

__global__ void wcvt_kernel(const float* __restrict__ W, short* __restrict__ Wt, int K) {
    int n = blockIdx.x;
    for (int k = threadIdx.x; k < K; k += blockDim.x)
        Wt[(size_t)n * K + k] = f2bf(W[(size_t)k * 256 + n]);
}

// ---------------- MFMA GEMM: H[M,256](bf16) = A[M,K](f32) @ Wt^T (bf16) ----------------
// block = 64 rows x 256 cols, 4 waves, wave = 32 rows x 128 cols (2x8 mfma tiles)
// no LDS, no barriers; A converted f32->bf16 in-register

__global__ __launch_bounds__(256) void gemm_mfma_kernel(const float* __restrict__ A,
                                                        const short* __restrict__ Wt,
                                                        short* __restrict__ H,
                                                        int M, int K) {
    int w = threadIdx.x >> 6;
    int lane = threadIdx.x & 63;
    int quad = lane >> 4, l16 = lane & 15;
    int wm = w & 1, wn = w >> 1;
    int m_base = blockIdx.x * 64 + wm * 32;
    int n_base = wn * 128;

    v4f acc[2][8] = {};

    for (int kt = 0; kt < K; kt += 32) {
        short8 a_frag[2];
#pragma unroll
        for (int mi = 0; mi < 2; mi++) {
            int m = m_base + mi * 16 + l16;
            if (m >= M) m = M - 1;
            const float* ap = A + (size_t)m * K + kt + quad * 8;
            float4 a0 = *(const float4*)ap;
            float4 a1 = *(const float4*)(ap + 4);
            a_frag[mi] = cvt_frag(a0, a1);
        }
        short8 b_frag[8];
#pragma unroll
        for (int nj = 0; nj < 8; nj++) {
            int n = n_base + nj * 16 + l16;
            b_frag[nj] = *(const short8*)(Wt + (size_t)n * K + kt + quad * 8);
        }
#pragma unroll
        for (int mi = 0; mi < 2; mi++)
#pragma unroll
            for (int nj = 0; nj < 8; nj++)
                acc[mi][nj] = __builtin_amdgcn_mfma_f32_16x16x32_bf16(a_frag[mi], b_frag[nj],
                                                                      acc[mi][nj], 0, 0, 0);
    }

#pragma unroll
    for (int mi = 0; mi < 2; mi++)
#pragma unroll
        for (int r = 0; r < 4; r++) {
            int row = m_base + mi * 16 + quad * 4 + r;
            if (row < M) {
#pragma unroll
                for (int nj = 0; nj < 8; nj++)
                    H[(size_t)row * HID + n_base + nj * 16 + l16] = f2bf(acc[mi][nj][r]);
            }
        }
}

// ---------------- attention logits per node/head (reads bf16 h) ----------------

__global__ void alpha_kernel(const short* __restrict__ h, const float* __restrict__ a_src,
                             const float* __restrict__ a_dst, float* __restrict__ alS,
                             float* __restrict__ alD, int n) {
    int idx = blockIdx.x * blockDim.x + threadIdx.x;  // node*8 + head
    if (idx >= n * HEADS) return;
    int head = idx & 7;
    int node = idx >> 3;
    const unsigned* hp = (const unsigned*)(h + (size_t)node * HID + head * CH);
    const float* as = a_src + head * CH;
    const float* ad = a_dst + head * CH;
    float s1 = 0.f, s2 = 0.f;
#pragma unroll
    for (int c = 0; c < 16; c++) {
        unsigned u = hp[c];
        float v0 = bflo(u), v1 = bfhi(u);
        s1 += v0 * as[2 * c] + v1 * as[2 * c + 1];
        s2 += v0 * ad[2 * c] + v1 * ad[2 * c + 1];
    }
    alS[idx] = s1;
    alD[idx] = s2;
}

// ---------------- attention stats ----------------

__global__ __launch_bounds__(256) void att_stats_kernel(const float* __restrict__ alS,
                                                        const float* __restrict__ alD,
                                                        const int* __restrict__ row_ptr,
                                                        const int* __restrict__ srcs,
                                                        float* __restrict__ mArr,
                                                        float* __restrict__ dArr, int n) {
    int node = blockIdx.x * 4 + (threadIdx.x >> 6);
    if (node >= n) return;
    int lane = threadIdx.x & 63;
    int eh = lane >> 3, head = lane & 7;
    int lo = row_ptr[node], hi = row_ptr[node + 1];
    float ald = alD[node * HEADS + head];

    float m = -1e30f;
    for (int base = lo; base < hi; base += 8) {
        int i = base + eh;
        float e = -1e30f;
        if (i < hi) {
            int s = srcs[i];
            e = alS[s * HEADS + head] + ald;
            e = e > 0.f ? e : NEG_SLOPE * e;
        }
        m = fmaxf(m, e);
    }
    m = fmaxf(m, __shfl_xor(m, 8));
    m = fmaxf(m, __shfl_xor(m, 16));
    m = fmaxf(m, __shfl_xor(m, 32));

    float denom = 0.f;
    for (int base = lo; base < hi; base += 8) {
        int i = base + eh;
        if (i < hi) {
            int s = srcs[i];
            float e = alS[s * HEADS + head] + ald;
            e = e > 0.f ? e : NEG_SLOPE * e;
            denom += __expf(e - m);
        }
    }
    denom += __shfl_xor(denom, 8);
    denom += __shfl_xor(denom, 16);
    denom += __shfl_xor(denom, 32);

    if (eh == 0) {
        mArr[node * HEADS + head] = m;
        dArr[node * HEADS + head] = denom;
    }
}

// ---------------- attention apply: bf16 gather, f32 accumulate ----------------

__global__ __launch_bounds__(256) void att_apply_kernel(const short* __restrict__ h,
                                                        const float* __restrict__ alS,
                                                        const float* __restrict__ alD,
                                                        const float* __restrict__ mArr,
                                                        const float* __restrict__ dArr,
                                                        const int* __restrict__ row_ptr,
                                                        const int* __restrict__ srcs,
                                                        const float* __restrict__ bias,
                                                        float* __restrict__ out, int n) {
    int node = blockIdx.x * 4 + (threadIdx.x >> 6);
    if (node >= n) return;
    int lane = threadIdx.x & 63;
    int head = lane >> 3;
    int lo = row_ptr[node], hi = row_ptr[node + 1];
    float ald = alD[node * HEADS + head];
    float m = mArr[node * HEADS + head];
    float inv = 1.0f / (dArr[node * HEADS + head] + 1e-16f);

    float4 acc = make_float4(0.f, 0.f, 0.f, 0.f);
    int i = lo;
    for (; i + 2 <= hi; i += 2) {
        int s0 = srcs[i], s1 = srcs[i + 1];
        float e0 = alS[s0 * HEADS + head] + ald;
        float e1 = alS[s1 * HEADS + head] + ald;
        e0 = e0 > 0.f ? e0 : NEG_SLOPE * e0;
        e1 = e1 > 0.f ? e1 : NEG_SLOPE * e1;
        float w0 = __expf(e0 - m);
        float w1 = __expf(e1 - m);
        uint2 u0 = *(const uint2*)&h[(size_t)s0 * HID + lane * 4];
        uint2 u1 = *(const uint2*)&h[(size_t)s1 * HID + lane * 4];
        acc.x += w0 * bflo(u0.x) + w1 * bflo(u1.x);
        acc.y += w0 * bfhi(u0.x) + w1 * bfhi(u1.x);
        acc.z += w0 * bflo(u0.y) + w1 * bflo(u1.y);
        acc.w += w0 * bfhi(u0.y) + w1 * bfhi(u1.y);
    }
    if (i < hi) {
        int s0 = srcs[i];
        float e0 = alS[s0 * HEADS + head] + ald;
        e0 = e0 > 0.f ? e0 : NEG_SLOPE * e0;
        float w0 = __expf(e0 - m);
        uint2 u0 = *(const uint2*)&h[(size_t)s0 * HID + lane * 4];
        acc.x += w0 * bflo(u0.x);
        acc.y += w0 * bfhi(u0.x);
        acc.z += w0 * bflo(u0.y);
        acc.w += w0 * bfhi(u0.y);
    }
    float4 b4 = *(const float4*)&bias[lane * 4];
    float4 o;
    o.x = acc.x * inv + b4.x;
    o.y = acc.y * inv + b4.y;
    o.z = acc.z * inv + b4.z;
    o.w = acc.w * inv + b4.w;
    *(float4*)&out[(size_t)node * HID + lane * 4] = o;
}

// ---------------- mean pool per graph ----------------

__global__ __launch_bounds__(256) void pool_kernel(const float* __restrict__ h,
                                                   const int* __restrict__ batch,
                                                   float* __restrict__ pooled, int n) {
    int g = blockIdx.x;
    int t = threadIdx.x;
    int lo = 0, hi = n;
    while (lo < hi) { int mid = (lo + hi) >> 1; if (batch[mid] < g) lo = mid + 1; else hi = mid; }
    int start = lo;
    lo = 0; hi = n;
    while (lo < hi) { int mid = (lo + hi) >> 1; if (batch[mid] < g + 1) lo = mid + 1; else hi = mid; }
    int end = lo;
    float acc = 0.f;
    for (int i = start; i < end; i++) acc += h[(size_t)i * HID + t];
    int cnt = end - start;
    pooled[g * HID + t] = acc / (float)(cnt > 0 ? cnt : 1);
}

// ---------------- final linear ----------------

__global__ void final_kernel(const float* __restrict__ pooled, const float* __restrict__ W,
                             const float* __restrict__ b, float* __restrict__ out) {
    int idx = blockIdx.x * blockDim.x + threadIdx.x;
    if (idx >= NGRAPH * 10) return;
    int g = idx / 10, o = idx % 10;
    float acc = b[o];
    for (int k = 0; k < HID; k++) acc += pooled[g * HID + k] * W[k * 10 + o];
    out[idx] = acc;
}

extern "C" void kernel_launch(void* const* d_in, const int* in_sizes, int n_in,
                              void* d_out, int out_size, void* d_ws, size_t ws_size,
                              hipStream_t stream) {
    const float* x      = (const float*)d_in[0];
    const int*   ei     = (const int*)d_in[1];
    const int*   batch  = (const int*)d_in[2];
    const float* W0     = (const float*)d_in[3];
    const float* a_src0 = (const float*)d_in[4];
    const float* a_dst0 = (const float*)d_in[5];
    const float* b0     = (const float*)d_in[6];
    const float* Wh     = (const float*)d_in[7];   // [2,256,256]
    const float* a_srch = (const float*)d_in[8];   // [2,8,32]
    const float* a_dsth = (const float*)d_in[9];
    const float* bh     = (const float*)d_in[10];  // [2,256]
    const float* W_lin  = (const float*)d_in[11];
    const float* b_lin  = (const float*)d_in[12];
    float* out = (float*)d_out;

    // workspace carve-up
    float* bufB   = (float*)d_ws;                    // 50000*256 f32 (layer output)
    short* hbuf   = (short*)(bufB + (size_t)NN * HID);  // 50000*256 bf16
    short* Wt0    = hbuf + (size_t)NN * HID;         // 256*128
    short* Wt1    = Wt0 + 256 * 128;                 // 256*256
    short* Wt2    = Wt1 + 256 * 256;                 // 256*256
    float* alS    = (float*)(Wt2 + 256 * 256);
    float* alD    = alS + (size_t)NN * HEADS;
    float* mArr   = alD + (size_t)NN * HEADS;
    float* dArr   = mArr + (size_t)NN * HEADS;
    float* pooled = dArr + (size_t)NN * HEADS;       // 128*256
    int* counts   = (int*)(pooled + NGRAPH * HID);   // 50000
    int* row_ptr  = counts + NN;                     // 50001
    int* cursor   = row_ptr + NN + 1;                // 50000
    int* srcs     = cursor + NN;                     // 850000
    int* partial  = srcs + (NE + NN);                // 64
    int* blockOff = partial + 64;                    // 64

    const int NEP = NE + NN;
    const int NB_SCAN = (NN + 1023) / 1024;

    // CSR build
    init_counts_kernel<<<(NN + 255) / 256, 256, 0, stream>>>(counts, NN);
    count_edges_kernel<<<(NE + 255) / 256, 256, 0, stream>>>(ei + NE, counts, NE);
    scan_part_kernel<<<NB_SCAN, 1024, 0, stream>>>(counts, partial, NN);
    scan_offsets_kernel<<<1, 64, 0, stream>>>(partial, blockOff, NB_SCAN);
    scan_final_kernel<<<NB_SCAN, 1024, 0, stream>>>(counts, blockOff, row_ptr, cursor, NN);
    scatter_kernel<<<(NEP + 255) / 256, 256, 0, stream>>>(ei, cursor, srcs, NE, NN);

    // weight prep
    wcvt_kernel<<<256, 256, 0, stream>>>(W0, Wt0, 128);
    wcvt_kernel<<<256, 256, 0, stream>>>(Wh, Wt1, 256);
    wcvt_kernel<<<256, 256, 0, stream>>>(Wh + 256 * 256, Wt2, 256);

    const int gemm_grid = (NN + 63) / 64;
    const int agg_grid = (NN + 3) / 4;

    // layer 0
    gemm_mfma_kernel<<<gemm_grid, 256, 0, stream>>>(x, Wt0, hbuf, NN, 128);
    alpha_kernel<<<(NN * HEADS + 255) / 256, 256, 0, stream>>>(hbuf, a_src0, a_dst0, alS, alD, NN);
    att_stats_kernel<<<agg_grid, 256, 0, stream>>>(alS, alD, row_ptr, srcs, mArr, dArr, NN);
    att_apply_kernel<<<agg_grid, 256, 0, stream>>>(hbuf, alS, alD, mArr, dArr, row_ptr, srcs, b0, bufB, NN);

    // hidden layers
    for (int l = 0; l < 2; l++) {
        const short* Wt = (l == 0) ? Wt1 : Wt2;
        const float* as = a_srch + (size_t)l * HEADS * CH;
        const float* ad = a_dsth + (size_t)l * HEADS * CH;
        const float* bb = bh + (size_t)l * HID;
        gemm_mfma_kernel<<<gemm_grid, 256, 0, stream>>>(bufB, Wt, hbuf, NN, 256);
        alpha_kernel<<<(NN * HEADS + 255) / 256, 256, 0, stream>>>(hbuf, as, ad, alS, alD, NN);
        att_stats_kernel<<<agg_grid, 256, 0, stream>>>(alS, alD, row_ptr, srcs, mArr, dArr, NN);
        att_apply_kernel<<<agg_grid, 256, 0, stream>>>(hbuf, alS, alD, mArr, dArr, row_ptr, srcs, bb, bufB, NN);
    }

    // pool + final linear
    pool_kernel<<<NGRAPH, 256, 0, stream>>>(bufB, batch, pooled, NN);
    final_kernel<<<(NGRAPH * 10 + 255) / 256, 256, 0, stream>>>(pooled, W_lin, b_lin, out);
}

// Round 4
// 621.898 us; speedup vs baseline: 2.5200x; 1.2586x over previous
//
#include <hip/hip_runtime.h>
#include <hip/hip_bf16.h>
#include <math.h>

#define NN 50000
#define NE 800000
#define NGRAPH 128
#define HEADS 8
#define CH 32
#define HID 256
#define NEG_SLOPE 0.2f

typedef __attribute__((ext_vector_type(8))) short short8;
typedef __attribute__((ext_vector_type(4))) float v4f;

__device__ inline float bflo(unsigned u) { return __builtin_bit_cast(float, u << 16); }
__device__ inline float bfhi(unsigned u) { return __builtin_bit_cast(float, u & 0xFFFF0000u); }
__device__ inline short f2bf(float f) {
    __hip_bfloat16 b = __float2bfloat16(f);
    return __builtin_bit_cast(short, b);
}
__device__ inline short8 cvt_frag(float4 a0, float4 a1) {
    union { short8 s; __hip_bfloat162 b[4]; } u;
    u.b[0] = __float22bfloat162_rn(make_float2(a0.x, a0.y));
    u.b[1] = __float22bfloat162_rn(make_float2(a0.z, a0.w));
    u.b[2] = __float22bfloat162_rn(make_float2(a1.x, a1.y));
    u.b[3] = __float22bfloat162_rn(make_float2(a1.z, a1.w));
    return u.s;
}

// ---------------- CSR build ----------------

__global__ void init_counts_kernel(int* counts, int n) {
    int i = blockIdx.x * blockDim.x + threadIdx.x;
    if (i < n) counts[i] = 1;  // self-loop
}

__global__ void count_edges_kernel(const int* __restrict__ dst, int* counts, int e) {
    int i = blockIdx.x * blockDim.x + threadIdx.x;
    if (i < e) atomicAdd(&counts[dst[i]], 1);
}

__device__ inline int wave_incl_scan(int v, int lane) {
#pragma unroll
    for (int off = 1; off < 64; off <<= 1) {
        int u = __shfl_up(v, off);
        if (lane >= off) v += u;
    }
    return v;
}

__global__ __launch_bounds__(1024) void scan_part_kernel(const int* __restrict__ counts,
                                                         int* partial, int n) {
    int i = blockIdx.x * 1024 + threadIdx.x;
    int v = (i < n) ? counts[i] : 0;
    int lane = threadIdx.x & 63, w = threadIdx.x >> 6;
    __shared__ int ws[16];
    int sv = wave_incl_scan(v, lane);
    if (lane == 63) ws[w] = sv;
    __syncthreads();
    if (threadIdx.x == 0) {
        int tot = 0;
#pragma unroll
        for (int j = 0; j < 16; j++) tot += ws[j];
        partial[blockIdx.x] = tot;
    }
}

__global__ void scan_offsets_kernel(const int* __restrict__ partial, int* blockOff, int nb) {
    int lane = threadIdx.x;
    int v = (lane < nb) ? partial[lane] : 0;
    int incl = wave_incl_scan(v, lane);
    if (lane < nb) blockOff[lane] = incl - v;
}

__global__ __launch_bounds__(1024) void scan_final_kernel(const int* __restrict__ counts,
                                                          const int* __restrict__ blockOff,
                                                          int* row_ptr, int* cursor, int n) {
    int i = blockIdx.x * 1024 + threadIdx.x;
    int v = (i < n) ? counts[i] : 0;
    int lane = threadIdx.x & 63, w = threadIdx.x >> 6;
    __shared__ int ws[17];
    int sv = wave_incl_scan(v, lane);
    if (lane == 63) ws[w] = sv;
    __syncthreads();
    if (w == 0) {
        int t = (lane < 16) ? ws[lane] : 0;
        int ts = wave_incl_scan(t, lane);
        if (lane < 16) ws[lane] = ts;
    }
    __syncthreads();
    int waveBase = (w > 0) ? ws[w - 1] : 0;
    int off = blockOff[blockIdx.x];
    int incl = waveBase + sv;
    if (i < n) {
        int ex = off + incl - v;
        row_ptr[i] = ex;
        cursor[i] = ex;
        if (i == n - 1) row_ptr[n] = off + incl;
    }
}

__global__ void scatter_kernel(const int* __restrict__ ei, int* cursor, int* srcs, int ne, int nn) {
    int i = blockIdx.x * blockDim.x + threadIdx.x;
    if (i < ne) {
        int s = ei[i];
        int d = ei[ne + i];
        int pos = atomicAdd(&cursor[d], 1);
        srcs[pos] = s;
    } else if (i < ne + nn) {
        int v = i - ne;
        int pos = atomicAdd(&cursor[v], 1);
        srcs[pos] = v;
    }
}

// ---------------- W convert+transpose: W[K,256] f32 -> Wt[256,K] bf16 ----------------

__global__ void wcvt_kernel(const float* __restrict__ W, short* __restrict__ Wt, int K) {
    int n = blockIdx.x;
    for (int k = threadIdx.x; k < K; k += blockDim.x)
        Wt[(size_t)n * K + k] = f2bf(W[(size_t)k * 256 + n]);
}

// ---------------- MFMA GEMM: H[M,256](bf16) = A[M,K](f32) @ Wt^T (bf16) ----------------

__global__ __launch_bounds__(256) void gemm_mfma_kernel(const float* __restrict__ A,
                                                        const short* __restrict__ Wt,
                                                        short* __restrict__ H,
                                                        int M, int K) {
    int w = threadIdx.x >> 6;
    int lane = threadIdx.x & 63;
    int quad = lane >> 4, l16 = lane & 15;
    int wm = w & 1, wn = w >> 1;
    int m_base = blockIdx.x * 64 + wm * 32;
    int n_base = wn * 128;

    v4f acc[2][8] = {};

    for (int kt = 0; kt < K; kt += 32) {
        short8 a_frag[2];
#pragma unroll
        for (int mi = 0; mi < 2; mi++) {
            int m = m_base + mi * 16 + l16;
            if (m >= M) m = M - 1;
            const float* ap = A + (size_t)m * K + kt + quad * 8;
            float4 a0 = *(const float4*)ap;
            float4 a1 = *(const float4*)(ap + 4);
            a_frag[mi] = cvt_frag(a0, a1);
        }
        short8 b_frag[8];
#pragma unroll
        for (int nj = 0; nj < 8; nj++) {
            int n = n_base + nj * 16 + l16;
            b_frag[nj] = *(const short8*)(Wt + (size_t)n * K + kt + quad * 8);
        }
#pragma unroll
        for (int mi = 0; mi < 2; mi++)
#pragma unroll
            for (int nj = 0; nj < 8; nj++)
                acc[mi][nj] = __builtin_amdgcn_mfma_f32_16x16x32_bf16(a_frag[mi], b_frag[nj],
                                                                      acc[mi][nj], 0, 0, 0);
    }

#pragma unroll
    for (int mi = 0; mi < 2; mi++)
#pragma unroll
        for (int r = 0; r < 4; r++) {
            int row = m_base + mi * 16 + quad * 4 + r;
            if (row < M) {
#pragma unroll
                for (int nj = 0; nj < 8; nj++)
                    H[(size_t)row * HID + n_base + nj * 16 + l16] = f2bf(acc[mi][nj][r]);
            }
        }
}

// ---------------- attention logits per node/head (reads bf16 h) ----------------

__global__ void alpha_kernel(const short* __restrict__ h, const float* __restrict__ a_src,
                             const float* __restrict__ a_dst, float* __restrict__ alS,
                             float* __restrict__ alD, int n) {
    int idx = blockIdx.x * blockDim.x + threadIdx.x;  // node*8 + head
    if (idx >= n * HEADS) return;
    int head = idx & 7;
    int node = idx >> 3;
    const unsigned* hp = (const unsigned*)(h + (size_t)node * HID + head * CH);
    const float* as = a_src + head * CH;
    const float* ad = a_dst + head * CH;
    float s1 = 0.f, s2 = 0.f;
#pragma unroll
    for (int c = 0; c < 16; c++) {
        unsigned u = hp[c];
        float v0 = bflo(u), v1 = bfhi(u);
        s1 += v0 * as[2 * c] + v1 * as[2 * c + 1];
        s2 += v0 * ad[2 * c] + v1 * ad[2 * c + 1];
    }
    alS[idx] = s1;
    alD[idx] = s2;
}

// ---------------- fused attention: online softmax + weighted gather ----------------
// one wave per node; lane owns channels [lane*4, lane*4+4); head = lane>>3

__global__ __launch_bounds__(256) void att_fused_kernel(const short* __restrict__ h,
                                                        const float* __restrict__ alS,
                                                        const float* __restrict__ alD,
                                                        const int* __restrict__ row_ptr,
                                                        const int* __restrict__ srcs,
                                                        const float* __restrict__ bias,
                                                        float* __restrict__ out, int n) {
    int node = blockIdx.x * 4 + (threadIdx.x >> 6);
    if (node >= n) return;
    int lane = threadIdx.x & 63;
    int head = lane >> 3;
    int lo = row_ptr[node], hi = row_ptr[node + 1];
    float ald = alD[node * HEADS + head];

    float m = -1e30f;
    float denom = 0.f;
    float4 acc = make_float4(0.f, 0.f, 0.f, 0.f);

    int i = lo;
    for (; i + 2 <= hi; i += 2) {
        int s0 = srcs[i], s1 = srcs[i + 1];
        float e0 = alS[s0 * HEADS + head] + ald;
        float e1 = alS[s1 * HEADS + head] + ald;
        e0 = e0 > 0.f ? e0 : NEG_SLOPE * e0;
        e1 = e1 > 0.f ? e1 : NEG_SLOPE * e1;
        float mn = fmaxf(m, fmaxf(e0, e1));
        float corr = __expf(m - mn);
        float w0 = __expf(e0 - mn);
        float w1 = __expf(e1 - mn);
        m = mn;
        uint2 u0 = *(const uint2*)&h[(size_t)s0 * HID + lane * 4];
        uint2 u1 = *(const uint2*)&h[(size_t)s1 * HID + lane * 4];
        denom = denom * corr + w0 + w1;
        acc.x = acc.x * corr + w0 * bflo(u0.x) + w1 * bflo(u1.x);
        acc.y = acc.y * corr + w0 * bfhi(u0.x) + w1 * bfhi(u1.x);
        acc.z = acc.z * corr + w0 * bflo(u0.y) + w1 * bflo(u1.y);
        acc.w = acc.w * corr + w0 * bfhi(u0.y) + w1 * bfhi(u1.y);
    }
    if (i < hi) {
        int s0 = srcs[i];
        float e0 = alS[s0 * HEADS + head] + ald;
        e0 = e0 > 0.f ? e0 : NEG_SLOPE * e0;
        float mn = fmaxf(m, e0);
        float corr = __expf(m - mn);
        float w0 = __expf(e0 - mn);
        uint2 u0 = *(const uint2*)&h[(size_t)s0 * HID + lane * 4];
        denom = denom * corr + w0;
        acc.x = acc.x * corr + w0 * bflo(u0.x);
        acc.y = acc.y * corr + w0 * bfhi(u0.x);
        acc.z = acc.z * corr + w0 * bflo(u0.y);
        acc.w = acc.w * corr + w0 * bfhi(u0.y);
    }
    float inv = 1.0f / (denom + 1e-16f);
    float4 b4 = *(const float4*)&bias[lane * 4];
    float4 o;
    o.x = acc.x * inv + b4.x;
    o.y = acc.y * inv + b4.y;
    o.z = acc.z * inv + b4.z;
    o.w = acc.w * inv + b4.w;
    *(float4*)&out[(size_t)node * HID + lane * 4] = o;
}

// ---------------- parallel mean pool: chunked accumulate + atomic flush ----------------
// batch is sorted; each block owns 64 nodes, thread t owns channel t

#define POOL_CHUNK 64

__global__ __launch_bounds__(256) void pool_accum_kernel(const float* __restrict__ h,
                                                         const int* __restrict__ batch,
                                                         float* __restrict__ pooled,
                                                         int* __restrict__ cnt, int n) {
    int c0 = blockIdx.x * POOL_CHUNK;
    int c1 = c0 + POOL_CHUNK; if (c1 > n) c1 = n;
    int t = threadIdx.x;
    int g_cur = batch[c0];
    float acc = 0.f;
    int run = 0;
    for (int i = c0; i < c1; i++) {
        int g = batch[i];
        if (g != g_cur) {
            atomicAdd(&pooled[g_cur * HID + t], acc);
            if (t == 0) atomicAdd(&cnt[g_cur], run);
            acc = 0.f; run = 0; g_cur = g;
        }
        acc += h[(size_t)i * HID + t];
        run++;
    }
    atomicAdd(&pooled[g_cur * HID + t], acc);
    if (t == 0) atomicAdd(&cnt[g_cur], run);
}

// ---------------- final linear (with mean divide) ----------------

__global__ void final_kernel(const float* __restrict__ pooled, const int* __restrict__ cnt,
                             const float* __restrict__ W, const float* __restrict__ b,
                             float* __restrict__ out) {
    int idx = blockIdx.x * blockDim.x + threadIdx.x;
    if (idx >= NGRAPH * 10) return;
    int g = idx / 10, o = idx % 10;
    int c = cnt[g];
    float inv = 1.0f / (float)(c > 0 ? c : 1);
    float acc = b[o];
    for (int k = 0; k < HID; k++) acc += pooled[g * HID + k] * inv * W[k * 10 + o];
    out[idx] = acc;
}

extern "C" void kernel_launch(void* const* d_in, const int* in_sizes, int n_in,
                              void* d_out, int out_size, void* d_ws, size_t ws_size,
                              hipStream_t stream) {
    const float* x      = (const float*)d_in[0];
    const int*   ei     = (const int*)d_in[1];
    const int*   batch  = (const int*)d_in[2];
    const float* W0     = (const float*)d_in[3];
    const float* a_src0 = (const float*)d_in[4];
    const float* a_dst0 = (const float*)d_in[5];
    const float* b0     = (const float*)d_in[6];
    const float* Wh     = (const float*)d_in[7];   // [2,256,256]
    const float* a_srch = (const float*)d_in[8];   // [2,8,32]
    const float* a_dsth = (const float*)d_in[9];
    const float* bh     = (const float*)d_in[10];  // [2,256]
    const float* W_lin  = (const float*)d_in[11];
    const float* b_lin  = (const float*)d_in[12];
    float* out = (float*)d_out;

    // workspace carve-up
    float* bufB   = (float*)d_ws;                       // 50000*256 f32
    short* hbuf   = (short*)(bufB + (size_t)NN * HID);  // 50000*256 bf16
    short* Wt0    = hbuf + (size_t)NN * HID;            // 256*128
    short* Wt1    = Wt0 + 256 * 128;                    // 256*256
    short* Wt2    = Wt1 + 256 * 256;                    // 256*256
    float* alS    = (float*)(Wt2 + 256 * 256);
    float* alD    = alS + (size_t)NN * HEADS;
    float* pooled = alD + (size_t)NN * HEADS;           // 128*256
    int* cnt      = (int*)(pooled + NGRAPH * HID);      // 128
    int* counts   = cnt + NGRAPH;                       // 50000
    int* row_ptr  = counts + NN;                        // 50001
    int* cursor   = row_ptr + NN + 1;                   // 50000
    int* srcs     = cursor + NN;                        // 850000
    int* partial  = srcs + (NE + NN);                   // 64
    int* blockOff = partial + 64;                       // 64

    const int NEP = NE + NN;
    const int NB_SCAN = (NN + 1023) / 1024;

    // CSR build
    init_counts_kernel<<<(NN + 255) / 256, 256, 0, stream>>>(counts, NN);
    count_edges_kernel<<<(NE + 255) / 256, 256, 0, stream>>>(ei + NE, counts, NE);
    scan_part_kernel<<<NB_SCAN, 1024, 0, stream>>>(counts, partial, NN);
    scan_offsets_kernel<<<1, 64, 0, stream>>>(partial, blockOff, NB_SCAN);
    scan_final_kernel<<<NB_SCAN, 1024, 0, stream>>>(counts, blockOff, row_ptr, cursor, NN);
    scatter_kernel<<<(NEP + 255) / 256, 256, 0, stream>>>(ei, cursor, srcs, NE, NN);

    // weight prep + pooled zero-init
    wcvt_kernel<<<256, 256, 0, stream>>>(W0, Wt0, 128);
    wcvt_kernel<<<256, 256, 0, stream>>>(Wh, Wt1, 256);
    wcvt_kernel<<<256, 256, 0, stream>>>(Wh + 256 * 256, Wt2, 256);
    hipMemsetAsync(pooled, 0, (NGRAPH * HID + NGRAPH) * sizeof(float), stream);

    const int gemm_grid = (NN + 63) / 64;
    const int agg_grid = (NN + 3) / 4;

    // layer 0
    gemm_mfma_kernel<<<gemm_grid, 256, 0, stream>>>(x, Wt0, hbuf, NN, 128);
    alpha_kernel<<<(NN * HEADS + 255) / 256, 256, 0, stream>>>(hbuf, a_src0, a_dst0, alS, alD, NN);
    att_fused_kernel<<<agg_grid, 256, 0, stream>>>(hbuf, alS, alD, row_ptr, srcs, b0, bufB, NN);

    // hidden layers
    for (int l = 0; l < 2; l++) {
        const short* Wt = (l == 0) ? Wt1 : Wt2;
        const float* as = a_srch + (size_t)l * HEADS * CH;
        const float* ad = a_dsth + (size_t)l * HEADS * CH;
        const float* bb = bh + (size_t)l * HID;
        gemm_mfma_kernel<<<gemm_grid, 256, 0, stream>>>(bufB, Wt, hbuf, NN, 256);
        alpha_kernel<<<(NN * HEADS + 255) / 256, 256, 0, stream>>>(hbuf, as, ad, alS, alD, NN);
        att_fused_kernel<<<agg_grid, 256, 0, stream>>>(hbuf, alS, alD, row_ptr, srcs, bb, bufB, NN);
    }

    // pool + final linear
    pool_accum_kernel<<<(NN + POOL_CHUNK - 1) / POOL_CHUNK, 256, 0, stream>>>(bufB, batch, pooled, cnt, NN);
    final_kernel<<<(NGRAPH * 10 + 255) / 256, 256, 0, stream>>>(pooled, cnt, W_lin, b_lin, out);
}

// Round 5
// 601.790 us; speedup vs baseline: 2.6042x; 1.0334x over previous
//
#include <hip/hip_runtime.h>
#include <hip/hip_bf16.h>
#include <math.h>

#define NN 50000
#define NE 800000
#define NGRAPH 128
#define HEADS 8
#define CH 32
#define HID 256
#define NEG_SLOPE 0.2f

typedef __attribute__((ext_vector_type(8))) short short8;
typedef __attribute__((ext_vector_type(4))) short short4v;
typedef __attribute__((ext_vector_type(4))) float v4f;

__device__ inline float bflo(unsigned u) { return __builtin_bit_cast(float, u << 16); }
__device__ inline float bfhi(unsigned u) { return __builtin_bit_cast(float, u & 0xFFFF0000u); }
__device__ inline float bf2f(short s) {
    return __builtin_bit_cast(float, ((unsigned)(unsigned short)s) << 16);
}
__device__ inline short f2bf(float f) {
    __hip_bfloat16 b = __float2bfloat16(f);
    return __builtin_bit_cast(short, b);
}

// ---------------- CSR build ----------------

__global__ void init_counts_kernel(int* counts, int n) {
    int i = blockIdx.x * blockDim.x + threadIdx.x;
    if (i < n) counts[i] = 1;  // self-loop
}

__global__ void count_edges_kernel(const int* __restrict__ dst, int* counts, int e) {
    int i = blockIdx.x * blockDim.x + threadIdx.x;
    if (i < e) atomicAdd(&counts[dst[i]], 1);
}

__device__ inline int wave_incl_scan(int v, int lane) {
#pragma unroll
    for (int off = 1; off < 64; off <<= 1) {
        int u = __shfl_up(v, off);
        if (lane >= off) v += u;
    }
    return v;
}

__global__ __launch_bounds__(1024) void scan_part_kernel(const int* __restrict__ counts,
                                                         int* partial, int n) {
    int i = blockIdx.x * 1024 + threadIdx.x;
    int v = (i < n) ? counts[i] : 0;
    int lane = threadIdx.x & 63, w = threadIdx.x >> 6;
    __shared__ int ws[16];
    int sv = wave_incl_scan(v, lane);
    if (lane == 63) ws[w] = sv;
    __syncthreads();
    if (threadIdx.x == 0) {
        int tot = 0;
#pragma unroll
        for (int j = 0; j < 16; j++) tot += ws[j];
        partial[blockIdx.x] = tot;
    }
}

__global__ void scan_offsets_kernel(const int* __restrict__ partial, int* blockOff, int nb) {
    int lane = threadIdx.x;
    int v = (lane < nb) ? partial[lane] : 0;
    int incl = wave_incl_scan(v, lane);
    if (lane < nb) blockOff[lane] = incl - v;
}

__global__ __launch_bounds__(1024) void scan_final_kernel(const int* __restrict__ counts,
                                                          const int* __restrict__ blockOff,
                                                          int* row_ptr, int* cursor, int n) {
    int i = blockIdx.x * 1024 + threadIdx.x;
    int v = (i < n) ? counts[i] : 0;
    int lane = threadIdx.x & 63, w = threadIdx.x >> 6;
    __shared__ int ws[17];
    int sv = wave_incl_scan(v, lane);
    if (lane == 63) ws[w] = sv;
    __syncthreads();
    if (w == 0) {
        int t = (lane < 16) ? ws[lane] : 0;
        int ts = wave_incl_scan(t, lane);
        if (lane < 16) ws[lane] = ts;
    }
    __syncthreads();
    int waveBase = (w > 0) ? ws[w - 1] : 0;
    int off = blockOff[blockIdx.x];
    int incl = waveBase + sv;
    if (i < n) {
        int ex = off + incl - v;
        row_ptr[i] = ex;
        cursor[i] = ex;
        if (i == n - 1) row_ptr[n] = off + incl;
    }
}

__global__ void scatter_kernel(const int* __restrict__ ei, int* cursor, int* srcs, int ne, int nn) {
    int i = blockIdx.x * blockDim.x + threadIdx.x;
    if (i < ne) {
        int s = ei[i];
        int d = ei[ne + i];
        int pos = atomicAdd(&cursor[d], 1);
        srcs[pos] = s;
    } else if (i < ne + nn) {
        int v = i - ne;
        int pos = atomicAdd(&cursor[v], 1);
        srcs[pos] = v;
    }
}

// ---------------- conversions ----------------

__global__ void xcvt_kernel(const float* __restrict__ x, short* __restrict__ xb, int n4) {
    int i = blockIdx.x * blockDim.x + threadIdx.x;
    if (i >= n4) return;
    float4 v = ((const float4*)x)[i];
    union { short4v s; __hip_bfloat162 b[2]; } p;
    p.b[0] = __float22bfloat162_rn(make_float2(v.x, v.y));
    p.b[1] = __float22bfloat162_rn(make_float2(v.z, v.w));
    ((short4v*)xb)[i] = p.s;
}

// W[K,256] f32 -> Wt[256,K] bf16
__global__ void wcvt_kernel(const float* __restrict__ W, short* __restrict__ Wt, int K) {
    int n = blockIdx.x;
    for (int k = threadIdx.x; k < K; k += blockDim.x)
        Wt[(size_t)n * K + k] = f2bf(W[(size_t)k * 256 + n]);
}

// ---------------- MFMA GEMM: H[M,256](bf16) = A[M,K](bf16) @ Wt^T (bf16) ----------------
// block = 64 rows x 256 cols, 4 waves, wave = 32 rows x 128 cols (2x8 mfma tiles)
// LDS epilogue for coalesced bf16 stores

#define EP_STRIDE 144  // halfwords; 4-row quad stride = 288 dwords = 8 mod 32 -> conflict-free

__global__ __launch_bounds__(256) void gemm_mfma_kernel(const short* __restrict__ A,
                                                        const short* __restrict__ Wt,
                                                        short* __restrict__ H,
                                                        int M, int K) {
    __shared__ short tile[4][32][EP_STRIDE];
    int w = threadIdx.x >> 6;
    int lane = threadIdx.x & 63;
    int quad = lane >> 4, l16 = lane & 15;
    int wm = w & 1, wn = w >> 1;
    int m_base = blockIdx.x * 64 + wm * 32;
    int n_base = wn * 128;

    v4f acc[2][8] = {};

    const short* aptr[2];
#pragma unroll
    for (int mi = 0; mi < 2; mi++) {
        int m = m_base + mi * 16 + l16;
        if (m >= M) m = M - 1;
        aptr[mi] = A + (size_t)m * K + quad * 8;
    }

    for (int kt = 0; kt < K; kt += 32) {
        short8 a_frag[2];
#pragma unroll
        for (int mi = 0; mi < 2; mi++)
            a_frag[mi] = *(const short8*)(aptr[mi] + kt);
        short8 b_frag[8];
#pragma unroll
        for (int nj = 0; nj < 8; nj++) {
            int n = n_base + nj * 16 + l16;
            b_frag[nj] = *(const short8*)(Wt + (size_t)n * K + kt + quad * 8);
        }
#pragma unroll
        for (int mi = 0; mi < 2; mi++)
#pragma unroll
            for (int nj = 0; nj < 8; nj++)
                acc[mi][nj] = __builtin_amdgcn_mfma_f32_16x16x32_bf16(a_frag[mi], b_frag[nj],
                                                                      acc[mi][nj], 0, 0, 0);
    }

    // stage wave tile in LDS (bank-conflict-free: quads land on disjoint octets)
#pragma unroll
    for (int mi = 0; mi < 2; mi++)
#pragma unroll
        for (int r = 0; r < 4; r++) {
            int rl = mi * 16 + quad * 4 + r;
#pragma unroll
            for (int nj = 0; nj < 8; nj++)
                tile[w][rl][nj * 16 + l16] = f2bf(acc[mi][nj][r]);
        }
    __syncthreads();

    // coalesced write-out: 16 lanes x 16B cover one row of 128 bf16
    int rq = lane >> 4;
#pragma unroll
    for (int it = 0; it < 8; it++) {
        int rl = it * 4 + rq;
        int row = m_base + rl;
        if (row < M) {
            short8 v = *(const short8*)&tile[w][rl][l16 * 8];
            *(short8*)&H[(size_t)row * HID + n_base + l16 * 8] = v;
        }
    }
}

// ---------------- attention logits per node/head (reads bf16 h) ----------------

__global__ void alpha_kernel(const short* __restrict__ h, const float* __restrict__ a_src,
                             const float* __restrict__ a_dst, float* __restrict__ alS,
                             float* __restrict__ alD, int n) {
    int idx = blockIdx.x * blockDim.x + threadIdx.x;  // node*8 + head
    if (idx >= n * HEADS) return;
    int head = idx & 7;
    int node = idx >> 3;
    const unsigned* hp = (const unsigned*)(h + (size_t)node * HID + head * CH);
    const float* as = a_src + head * CH;
    const float* ad = a_dst + head * CH;
    float s1 = 0.f, s2 = 0.f;
#pragma unroll
    for (int c = 0; c < 16; c++) {
        unsigned u = hp[c];
        float v0 = bflo(u), v1 = bfhi(u);
        s1 += v0 * as[2 * c] + v1 * as[2 * c + 1];
        s2 += v0 * ad[2 * c] + v1 * ad[2 * c + 1];
    }
    alS[idx] = s1;
    alD[idx] = s2;
}

// ---------------- fused attention: online softmax + weighted gather, bf16 in/out ----------------
// one wave per node; lane owns channels [lane*4, lane*4+4); head = lane>>3

__global__ __launch_bounds__(256) void att_fused_kernel(const short* __restrict__ h,
                                                        const float* __restrict__ alS,
                                                        const float* __restrict__ alD,
                                                        const int* __restrict__ row_ptr,
                                                        const int* __restrict__ srcs,
                                                        const float* __restrict__ bias,
                                                        short* __restrict__ out, int n) {
    int node = blockIdx.x * 4 + (threadIdx.x >> 6);
    if (node >= n) return;
    int lane = threadIdx.x & 63;
    int head = lane >> 3;
    int lo = row_ptr[node], hi = row_ptr[node + 1];
    float ald = alD[node * HEADS + head];

    float m = -1e30f;
    float denom = 0.f;
    float4 acc = make_float4(0.f, 0.f, 0.f, 0.f);

    int i = lo;
    for (; i + 2 <= hi; i += 2) {
        int s0 = srcs[i], s1 = srcs[i + 1];
        float e0 = alS[s0 * HEADS + head] + ald;
        float e1 = alS[s1 * HEADS + head] + ald;
        e0 = e0 > 0.f ? e0 : NEG_SLOPE * e0;
        e1 = e1 > 0.f ? e1 : NEG_SLOPE * e1;
        float mn = fmaxf(m, fmaxf(e0, e1));
        float corr = __expf(m - mn);
        float w0 = __expf(e0 - mn);
        float w1 = __expf(e1 - mn);
        m = mn;
        uint2 u0 = *(const uint2*)&h[(size_t)s0 * HID + lane * 4];
        uint2 u1 = *(const uint2*)&h[(size_t)s1 * HID + lane * 4];
        denom = denom * corr + w0 + w1;
        acc.x = acc.x * corr + w0 * bflo(u0.x) + w1 * bflo(u1.x);
        acc.y = acc.y * corr + w0 * bfhi(u0.x) + w1 * bfhi(u1.x);
        acc.z = acc.z * corr + w0 * bflo(u0.y) + w1 * bflo(u1.y);
        acc.w = acc.w * corr + w0 * bfhi(u0.y) + w1 * bfhi(u1.y);
    }
    if (i < hi) {
        int s0 = srcs[i];
        float e0 = alS[s0 * HEADS + head] + ald;
        e0 = e0 > 0.f ? e0 : NEG_SLOPE * e0;
        float mn = fmaxf(m, e0);
        float corr = __expf(m - mn);
        float w0 = __expf(e0 - mn);
        uint2 u0 = *(const uint2*)&h[(size_t)s0 * HID + lane * 4];
        denom = denom * corr + w0;
        acc.x = acc.x * corr + w0 * bflo(u0.x);
        acc.y = acc.y * corr + w0 * bfhi(u0.x);
        acc.z = acc.z * corr + w0 * bflo(u0.y);
        acc.w = acc.w * corr + w0 * bfhi(u0.y);
    }
    float inv = 1.0f / (denom + 1e-16f);
    float4 b4 = *(const float4*)&bias[lane * 4];
    union { uint2 u; __hip_bfloat162 b[2]; } p;
    p.b[0] = __float22bfloat162_rn(make_float2(acc.x * inv + b4.x, acc.y * inv + b4.y));
    p.b[1] = __float22bfloat162_rn(make_float2(acc.z * inv + b4.z, acc.w * inv + b4.w));
    *(uint2*)&out[(size_t)node * HID + lane * 4] = p.u;
}

// ---------------- parallel mean pool (bf16 input) ----------------

#define POOL_CHUNK 64

__global__ __launch_bounds__(256) void pool_accum_kernel(const short* __restrict__ h,
                                                         const int* __restrict__ batch,
                                                         float* __restrict__ pooled,
                                                         int* __restrict__ cnt, int n) {
    int c0 = blockIdx.x * POOL_CHUNK;
    int c1 = c0 + POOL_CHUNK; if (c1 > n) c1 = n;
    int t = threadIdx.x;
    int g_cur = batch[c0];
    float acc = 0.f;
    int run = 0;
    for (int i = c0; i < c1; i++) {
        int g = batch[i];
        if (g != g_cur) {
            atomicAdd(&pooled[g_cur * HID + t], acc);
            if (t == 0) atomicAdd(&cnt[g_cur], run);
            acc = 0.f; run = 0; g_cur = g;
        }
        acc += bf2f(h[(size_t)i * HID + t]);
        run++;
    }
    atomicAdd(&pooled[g_cur * HID + t], acc);
    if (t == 0) atomicAdd(&cnt[g_cur], run);
}

// ---------------- final linear (with mean divide) ----------------

__global__ void final_kernel(const float* __restrict__ pooled, const int* __restrict__ cnt,
                             const float* __restrict__ W, const float* __restrict__ b,
                             float* __restrict__ out) {
    int idx = blockIdx.x * blockDim.x + threadIdx.x;
    if (idx >= NGRAPH * 10) return;
    int g = idx / 10, o = idx % 10;
    int c = cnt[g];
    float inv = 1.0f / (float)(c > 0 ? c : 1);
    float acc = b[o];
    for (int k = 0; k < HID; k++) acc += pooled[g * HID + k] * inv * W[k * 10 + o];
    out[idx] = acc;
}

extern "C" void kernel_launch(void* const* d_in, const int* in_sizes, int n_in,
                              void* d_out, int out_size, void* d_ws, size_t ws_size,
                              hipStream_t stream) {
    const float* x      = (const float*)d_in[0];
    const int*   ei     = (const int*)d_in[1];
    const int*   batch  = (const int*)d_in[2];
    const float* W0     = (const float*)d_in[3];
    const float* a_src0 = (const float*)d_in[4];
    const float* a_dst0 = (const float*)d_in[5];
    const float* b0     = (const float*)d_in[6];
    const float* Wh     = (const float*)d_in[7];   // [2,256,256]
    const float* a_srch = (const float*)d_in[8];   // [2,8,32]
    const float* a_dsth = (const float*)d_in[9];
    const float* bh     = (const float*)d_in[10];  // [2,256]
    const float* W_lin  = (const float*)d_in[11];
    const float* b_lin  = (const float*)d_in[12];
    float* out = (float*)d_out;

    // workspace carve-up (all bf16 buffers are even element counts -> 4B aligned)
    short* hA     = (short*)d_ws;                    // 50000*256 bf16 (GEMM out)
    short* hB     = hA + (size_t)NN * HID;           // 50000*256 bf16 (att out)
    short* xb     = hB + (size_t)NN * HID;           // 50000*128 bf16
    short* Wt0    = xb + (size_t)NN * 128;           // 256*128
    short* Wt1    = Wt0 + 256 * 128;                 // 256*256
    short* Wt2    = Wt1 + 256 * 256;                 // 256*256
    float* alS    = (float*)(Wt2 + 256 * 256);
    float* alD    = alS + (size_t)NN * HEADS;
    float* pooled = alD + (size_t)NN * HEADS;        // 128*256
    int* cnt      = (int*)(pooled + NGRAPH * HID);   // 128
    int* counts   = cnt + NGRAPH;                    // 50000
    int* row_ptr  = counts + NN;                     // 50001
    int* cursor   = row_ptr + NN + 1;                // 50000
    int* srcs     = cursor + NN;                     // 850000
    int* partial  = srcs + (NE + NN);                // 64
    int* blockOff = partial + 64;                    // 64

    const int NEP = NE + NN;
    const int NB_SCAN = (NN + 1023) / 1024;

    // CSR build
    init_counts_kernel<<<(NN + 255) / 256, 256, 0, stream>>>(counts, NN);
    count_edges_kernel<<<(NE + 255) / 256, 256, 0, stream>>>(ei + NE, counts, NE);
    scan_part_kernel<<<NB_SCAN, 1024, 0, stream>>>(counts, partial, NN);
    scan_offsets_kernel<<<1, 64, 0, stream>>>(partial, blockOff, NB_SCAN);
    scan_final_kernel<<<NB_SCAN, 1024, 0, stream>>>(counts, blockOff, row_ptr, cursor, NN);
    scatter_kernel<<<(NEP + 255) / 256, 256, 0, stream>>>(ei, cursor, srcs, NE, NN);

    // weight/x prep + pooled zero-init
    wcvt_kernel<<<256, 256, 0, stream>>>(W0, Wt0, 128);
    wcvt_kernel<<<256, 256, 0, stream>>>(Wh, Wt1, 256);
    wcvt_kernel<<<256, 256, 0, stream>>>(Wh + 256 * 256, Wt2, 256);
    xcvt_kernel<<<(NN * 128 / 4 + 255) / 256, 256, 0, stream>>>(x, xb, NN * 128 / 4);
    hipMemsetAsync(pooled, 0, (NGRAPH * HID + NGRAPH) * sizeof(float), stream);

    const int gemm_grid = (NN + 63) / 64;
    const int agg_grid = (NN + 3) / 4;

    // layer 0
    gemm_mfma_kernel<<<gemm_grid, 256, 0, stream>>>(xb, Wt0, hA, NN, 128);
    alpha_kernel<<<(NN * HEADS + 255) / 256, 256, 0, stream>>>(hA, a_src0, a_dst0, alS, alD, NN);
    att_fused_kernel<<<agg_grid, 256, 0, stream>>>(hA, alS, alD, row_ptr, srcs, b0, hB, NN);

    // hidden layers
    for (int l = 0; l < 2; l++) {
        const short* Wt = (l == 0) ? Wt1 : Wt2;
        const float* as = a_srch + (size_t)l * HEADS * CH;
        const float* ad = a_dsth + (size_t)l * HEADS * CH;
        const float* bb = bh + (size_t)l * HID;
        gemm_mfma_kernel<<<gemm_grid, 256, 0, stream>>>(hB, Wt, hA, NN, 256);
        alpha_kernel<<<(NN * HEADS + 255) / 256, 256, 0, stream>>>(hA, as, ad, alS, alD, NN);
        att_fused_kernel<<<agg_grid, 256, 0, stream>>>(hA, alS, alD, row_ptr, srcs, bb, hB, NN);
    }

    // pool + final linear
    pool_accum_kernel<<<(NN + POOL_CHUNK - 1) / POOL_CHUNK, 256, 0, stream>>>(hB, batch, pooled, cnt, NN);
    final_kernel<<<(NGRAPH * 10 + 255) / 256, 256, 0, stream>>>(pooled, cnt, W_lin, b_lin, out);
}